// Round 15
// baseline (2779.209 us; speedup 1.0000x reference)
//
#include <hip/hip_runtime.h>
#include <stdint.h>

// Problem constants
#define N_ROWS 32768
#define KCODES 8192
#define DIM    512
#define DECAYF 0.8f
#define EPSF   1e-5f
#define CAP    96

// d_out layout (float32, reference return order)
#define OUT_QUANT 0
#define OUT_IND   (N_ROWS * DIM)
#define OUT_CSN   (OUT_IND + N_ROWS)
#define OUT_AVG   (OUT_CSN + KCODES)
#define OUT_NORM  (OUT_AVG + KCODES * DIM)

// During dist_k the quant region (64 MiB) holds Xh+Xm planes; rewritten by quant_slot_k.
// csn/avg/norm regions are written ONLY by csum_k (post-dist).
// ws: [0,256K) best; [256K,288K) norm2; [288K,+128) partial[32];
//     [1MiB) Eh, Em (8 MiB each); [20MiB) cnt u32[8192]; then rowlist u32[8192*CAP].

typedef _Float16 f16x8 __attribute__((ext_vector_type(8)));
typedef __attribute__((ext_vector_type(4))) float f32x4;

__device__ __forceinline__ unsigned int enc_f(float v) {
    unsigned int b = __float_as_uint(v);
    return (b & 0x80000000u) ? ~b : (b | 0x80000000u);
}

__device__ __forceinline__ void gl16(const _Float16* g, const char* lds) {
    __builtin_amdgcn_global_load_lds(
        (const __attribute__((address_space(1))) unsigned int*)g,
        (__attribute__((address_space(3))) unsigned int*)lds, 16, 0, 0);
}

// ---- merged prep: [0,8192) split X (+best/cnt init); [8192,10240) split E (+norm2);
// ---- [10240,10272) partial cs sums (for S = 0.8*sum(cs) + 0.2*N_ROWS) ----
__global__ void prep_k(const float* __restrict__ x, const float* __restrict__ embed,
                       _Float16* __restrict__ Xh, _Float16* __restrict__ Xm,
                       _Float16* __restrict__ Eh, _Float16* __restrict__ Em,
                       unsigned long long* __restrict__ best, unsigned int* __restrict__ cnt,
                       const float* __restrict__ cs, float* __restrict__ partial,
                       float* __restrict__ norm2) {
    if (blockIdx.x < 8192) {
        int i = blockIdx.x * 256 + threadIdx.x;        // < 2097152
        if (i < N_ROWS) best[i] = 0ull;
        if (i < KCODES) cnt[i] = 0u;
        const float4* s4 = (const float4*)x;
        float4 v0 = s4[(size_t)i * 2], v1 = s4[(size_t)i * 2 + 1];
        float f[8] = {v0.x, v0.y, v0.z, v0.w, v1.x, v1.y, v1.z, v1.w};
        f16x8 hv, mv;
        #pragma unroll
        for (int j = 0; j < 8; ++j) {
            _Float16 h = (_Float16)f[j];
            float r = f[j] - (float)h;
            hv[j] = h;
            mv[j] = (_Float16)(r * 1024.0f);
        }
        *(f16x8*)(Xh + (size_t)i * 8) = hv;
        *(f16x8*)(Xm + (size_t)i * 8) = mv;
    } else if (blockIdx.x < 10240) {
        int i = (blockIdx.x - 8192) * 256 + threadIdx.x;   // < 524288
        const float4* s4 = (const float4*)embed;
        float4 v0 = s4[(size_t)i * 2], v1 = s4[(size_t)i * 2 + 1];
        float f[8] = {v0.x, v0.y, v0.z, v0.w, v1.x, v1.y, v1.z, v1.w};
        f16x8 hv, mv;
        float s = 0.f;
        #pragma unroll
        for (int j = 0; j < 8; ++j) {
            _Float16 h = (_Float16)f[j];
            float r = f[j] - (float)h;
            hv[j] = h;
            mv[j] = (_Float16)(r * 1024.0f);
            s += f[j] * f[j];
        }
        *(f16x8*)(Eh + (size_t)i * 8) = hv;
        *(f16x8*)(Em + (size_t)i * 8) = mv;
        #pragma unroll
        for (int off = 32; off; off >>= 1) s += __shfl_down(s, off);
        if ((threadIdx.x & 63) == 0) norm2[i >> 6] = s;
    } else {
        // partial[b] = 0.8 * sum(cs[b*256 .. b*256+255])
        __shared__ float red[4];
        int b = blockIdx.x - 10240;                    // 0..31
        float s = DECAYF * cs[b * 256 + threadIdx.x];
        #pragma unroll
        for (int off = 32; off; off >>= 1) s += __shfl_down(s, off);
        if ((threadIdx.x & 63) == 0) red[threadIdx.x >> 6] = s;
        __syncthreads();
        if (threadIdx.x == 0) partial[b] = red[0] + red[1] + red[2] + red[3];
    }
}

// ---- K1: f16 3-pass dual-acc MFMA GEMM, counted-vmcnt 2-buffer pipeline (R6/R12, 846us) ----
#define BM 128
#define BN 128
#define BK 32
#define TILEB 8192      // bytes per plane tile: 128 rows x 32 f16
#define LBUF  32768     // one LDS buffer: 4 planes (Ah Am Bh Bm)

__global__ __launch_bounds__(256, 2) void dist_k(
    const _Float16* __restrict__ Xh, const _Float16* __restrict__ Xm,
    const _Float16* __restrict__ Eh, const _Float16* __restrict__ Em,
    const float* __restrict__ norm2, unsigned long long* __restrict__ best)
{
    __shared__ _Float16 smem[2 * 4 * 4096];   // 64 KiB: 2 x (Ah Am Bh Bm)
    char* sb = (char*)smem;

    const int tid = threadIdx.x;
    const int w = tid >> 6, l = tid & 63;

    // XCD column-band mapping: XCD (b&7) owns 8 consecutive bx; bx-minor, by-major.
    int b = blockIdx.x;
    int xcd = b & 7;
    int local = b >> 3;
    int bxl = local & 7;
    int by = local >> 3;
    int bx = xcd * 8 + bxl;
    const int rBase = by * BM, cBase = bx * BN;

    // staging: 2 rounds/plane, linear LDS dest, pre-swizzled source (granule ^ (row>>1)&3)
    int o0 = (w << 10) | (l << 4);
    int o1 = o0 + 4096;
    int row0 = o0 >> 6, kb0 = (o0 >> 4) & 3;
    int row1 = o1 >> 6, kb1 = (o1 >> 4) & 3;
    int c0 = (kb0 ^ ((row0 >> 1) & 3)) << 3;
    int c1 = (kb1 ^ ((row1 >> 1) & 3)) << 3;
    unsigned offA0 = (unsigned)(rBase + row0) * DIM + c0;
    unsigned offA1 = (unsigned)(rBase + row1) * DIM + c1;
    unsigned offB0 = (unsigned)(cBase + row0) * DIM + c0;
    unsigned offB1 = (unsigned)(cBase + row1) * DIM + c1;
    const int w1024 = w << 10;

    const int wr = w >> 1, wc = w & 1;     // 2x2 wave grid, 64x64 output each
    const int ln = l & 15, kq = l >> 4;

    // ds_read bases (proven conflict-free 16x16 geometry from R3)
    const int rA = wr * 64 + ln;
    const int baA = rA * 64 + ((kq ^ ((rA >> 1) & 3)) << 4);
    const int rB = wc * 64 + ln;
    const int baB = rB * 64 + ((kq ^ ((rB >> 1) & 3)) << 4);

    f32x4 acc1[4][4], acc2[4][4];
    #pragma unroll
    for (int i = 0; i < 4; ++i)
        #pragma unroll
        for (int j = 0; j < 4; ++j) {
            acc1[i][j] = (f32x4){0.f, 0.f, 0.f, 0.f};
            acc2[i][j] = (f32x4){0.f, 0.f, 0.f, 0.f};
        }

    #define STAGE(BUFOFF, D0) { \
        gl16(Xh + offA0 + (D0), sb + (BUFOFF) + 0 * TILEB + w1024); \
        gl16(Xh + offA1 + (D0), sb + (BUFOFF) + 0 * TILEB + 4096 + w1024); \
        gl16(Xm + offA0 + (D0), sb + (BUFOFF) + 1 * TILEB + w1024); \
        gl16(Xm + offA1 + (D0), sb + (BUFOFF) + 1 * TILEB + 4096 + w1024); \
        gl16(Eh + offB0 + (D0), sb + (BUFOFF) + 2 * TILEB + w1024); \
        gl16(Eh + offB1 + (D0), sb + (BUFOFF) + 2 * TILEB + 4096 + w1024); \
        gl16(Em + offB0 + (D0), sb + (BUFOFF) + 3 * TILEB + w1024); \
        gl16(Em + offB1 + (D0), sb + (BUFOFF) + 3 * TILEB + 4096 + w1024); \
    }

    #define COMPUTE(BUFOFF) { \
        f16x8 ah[4], am[4], bh[4], bm[4]; \
        _Pragma("unroll") \
        for (int ai = 0; ai < 4; ++ai) { \
            ah[ai] = *(const f16x8*)(sb + (BUFOFF) + 0 * TILEB + baA + ai * 1024); \
            am[ai] = *(const f16x8*)(sb + (BUFOFF) + 1 * TILEB + baA + ai * 1024); \
        } \
        _Pragma("unroll") \
        for (int bj = 0; bj < 4; ++bj) { \
            bh[bj] = *(const f16x8*)(sb + (BUFOFF) + 2 * TILEB + baB + bj * 1024); \
            bm[bj] = *(const f16x8*)(sb + (BUFOFF) + 3 * TILEB + baB + bj * 1024); \
        } \
        _Pragma("unroll") \
        for (int bj = 0; bj < 4; ++bj) \
            _Pragma("unroll") \
            for (int ai = 0; ai < 4; ++ai) \
                acc1[ai][bj] = __builtin_amdgcn_mfma_f32_16x16x32_f16(ah[ai], bh[bj], acc1[ai][bj], 0, 0, 0); \
        _Pragma("unroll") \
        for (int bj = 0; bj < 4; ++bj) \
            _Pragma("unroll") \
            for (int ai = 0; ai < 4; ++ai) \
                acc2[ai][bj] = __builtin_amdgcn_mfma_f32_16x16x32_f16(ah[ai], bm[bj], acc2[ai][bj], 0, 0, 0); \
        _Pragma("unroll") \
        for (int bj = 0; bj < 4; ++bj) \
            _Pragma("unroll") \
            for (int ai = 0; ai < 4; ++ai) \
                acc2[ai][bj] = __builtin_amdgcn_mfma_f32_16x16x32_f16(am[ai], bh[bj], acc2[ai][bj], 0, 0, 0); \
    }

    // T4 counted-vmcnt pipeline: never drain in-flight prefetch (R6-proven).
    STAGE(0, 0)
    #pragma unroll
    for (int it = 0; it < 8; ++it) {
        int d0 = it * 64;
        STAGE(LBUF, d0 + 32)
        asm volatile("s_waitcnt vmcnt(8)" ::: "memory");
        __builtin_amdgcn_s_barrier();
        __builtin_amdgcn_sched_barrier(0);
        COMPUTE(0)
        __builtin_amdgcn_s_barrier();
        if (it < 7) {
            STAGE(0, d0 + 64)
            asm volatile("s_waitcnt vmcnt(8)" ::: "memory");
        } else {
            asm volatile("s_waitcnt vmcnt(0)" ::: "memory");
        }
        __builtin_amdgcn_s_barrier();
        __builtin_amdgcn_sched_barrier(0);
        COMPUTE(LBUF)
        __builtin_amdgcn_s_barrier();
    }
    #undef STAGE
    #undef COMPUTE

    // ---- epilogue: dot = acc1 + 2^-10 * acc2 ; dist = 2*dot - ||e||^2 ; argmax ----
    const float S = 0.0009765625f;   // 2^-10
    float n2v[4];
    #pragma unroll
    for (int bj = 0; bj < 4; ++bj)
        n2v[bj] = norm2[cBase + wc * 64 + bj * 16 + ln];

    #pragma unroll
    for (int ai = 0; ai < 4; ++ai) {
        #pragma unroll
        for (int r = 0; r < 4; ++r) {
            float bval = -3.4e38f;
            int bidx = 0;
            #pragma unroll
            for (int bj = 0; bj < 4; ++bj) {
                float v = 2.f * (acc1[ai][bj][r] + S * acc2[ai][bj][r]) - n2v[bj];
                if (v > bval) { bval = v; bidx = cBase + wc * 64 + bj * 16 + ln; }
            }
            #pragma unroll
            for (int off = 1; off < 16; off <<= 1) {
                float ov = __shfl_xor(bval, off);
                int   oi = __shfl_xor(bidx, off);
                if (ov > bval || (ov == bval && oi < bidx)) { bval = ov; bidx = oi; }
            }
            if (ln == 0) {
                unsigned long long key =
                    ((unsigned long long)enc_f(bval) << 32) | (unsigned int)(~(unsigned int)bidx);
                atomicMax(&best[rBase + wr * 64 + ai * 16 + kq * 4 + r], key);
            }
        }
    }
}

// ---- phase A: gather quantize + slot allocation (4 rows per 256-thread block) ----
__global__ void quant_slot_k(const float* __restrict__ embed,
                             const unsigned long long* __restrict__ best,
                             unsigned int* __restrict__ cnt, unsigned int* __restrict__ rowlist,
                             float* __restrict__ out) {
    int row = blockIdx.x * 4 + (threadIdx.x >> 6);
    int lane = threadIdx.x & 63;
    int idx = (int)(~(unsigned int)best[row]);
    const float4* e = (const float4*)(embed + (size_t)idx * DIM);
    float4* q = (float4*)(out + OUT_QUANT + (size_t)row * DIM);
    q[lane] = e[lane];
    q[lane + 64] = e[lane + 64];
    if (lane == 0) {
        out[OUT_IND + row] = (float)idx;
        unsigned pos = atomicAdd(&cnt[idx], 1u);
        if (pos < CAP) rowlist[idx * CAP + pos] = (unsigned)row;
    }
}

// ---- phase B: per-code fused EMA + smoothing + normalize (one block per code) ----
// csn = 0.8*cs + 0.2*n ; avg = 0.8*eavg + 0.2*sum ; S = 0.8*sum(cs) + 0.2*N_ROWS ;
// norm = avg * (S + K*eps) / ((csn+eps)*S).  No atomics; n>CAP falls back to full scan.
__global__ void csum_k(const float* __restrict__ x, const float* __restrict__ eavg,
                       const float* __restrict__ cs, const unsigned int* __restrict__ cnt,
                       const unsigned int* __restrict__ rowlist,
                       const unsigned long long* __restrict__ best,
                       const float* __restrict__ partial, float* __restrict__ out) {
    int code = blockIdx.x, lane = threadIdx.x;
    int n = (int)cnt[code];
    float4 a0 = {0.f, 0.f, 0.f, 0.f}, a1 = {0.f, 0.f, 0.f, 0.f};
    if (n <= CAP) {
        for (int t = 0; t < n; ++t) {
            int row = (int)rowlist[code * CAP + t];
            const float4* xr = (const float4*)(x + (size_t)row * DIM);
            float4 v0 = xr[lane], v1 = xr[lane + 64];
            a0.x += v0.x; a0.y += v0.y; a0.z += v0.z; a0.w += v0.w;
            a1.x += v1.x; a1.y += v1.y; a1.z += v1.z; a1.w += v1.w;
        }
    } else {   // overflow guard: scan all assignments (correct always; needed ~never)
        for (int row = 0; row < N_ROWS; ++row) {
            if ((int)(~(unsigned int)best[row]) != code) continue;
            const float4* xr = (const float4*)(x + (size_t)row * DIM);
            float4 v0 = xr[lane], v1 = xr[lane + 64];
            a0.x += v0.x; a0.y += v0.y; a0.z += v0.z; a0.w += v0.w;
            a1.x += v1.x; a1.y += v1.y; a1.z += v1.z; a1.w += v1.w;
        }
    }
    float S = 0.2f * (float)N_ROWS;
    #pragma unroll
    for (int j = 0; j < 32; ++j) S += partial[j];
    float csn = DECAYF * cs[code] + 0.2f * (float)n;
    float inv = (S + (float)KCODES * EPSF) / ((csn + EPSF) * S);
    if (lane == 0) out[OUT_CSN + code] = csn;

    const float4* ev = (const float4*)(eavg + (size_t)code * DIM);
    float4 e0 = ev[lane], e1 = ev[lane + 64];
    float4 av0, av1, nm0, nm1;
    av0.x = DECAYF * e0.x + 0.2f * a0.x; av0.y = DECAYF * e0.y + 0.2f * a0.y;
    av0.z = DECAYF * e0.z + 0.2f * a0.z; av0.w = DECAYF * e0.w + 0.2f * a0.w;
    av1.x = DECAYF * e1.x + 0.2f * a1.x; av1.y = DECAYF * e1.y + 0.2f * a1.y;
    av1.z = DECAYF * e1.z + 0.2f * a1.z; av1.w = DECAYF * e1.w + 0.2f * a1.w;
    nm0.x = av0.x * inv; nm0.y = av0.y * inv; nm0.z = av0.z * inv; nm0.w = av0.w * inv;
    nm1.x = av1.x * inv; nm1.y = av1.y * inv; nm1.z = av1.z * inv; nm1.w = av1.w * inv;
    float4* av = (float4*)(out + OUT_AVG + (size_t)code * DIM);
    float4* nm = (float4*)(out + OUT_NORM + (size_t)code * DIM);
    av[lane] = av0; av[lane + 64] = av1;
    nm[lane] = nm0; nm[lane + 64] = nm1;
}

extern "C" void kernel_launch(void* const* d_in, const int* in_sizes, int n_in,
                              void* d_out, int out_size, void* d_ws, size_t ws_size,
                              hipStream_t stream) {
    const float* x     = (const float*)d_in[0];
    const float* embed = (const float*)d_in[1];
    const float* cs    = (const float*)d_in[2];
    const float* eavg  = (const float*)d_in[3];
    float* out = (float*)d_out;
    char*  w   = (char*)d_ws;

    unsigned long long* best = (unsigned long long*)w;
    float* norm2   = (float*)(w + 262144);
    float* partial = (float*)(w + 294912);
    _Float16* Eh = (_Float16*)(w + (1u << 20));
    _Float16* Em = Eh + (size_t)KCODES * DIM;
    unsigned int* cnt     = (unsigned int*)(w + (20u << 20));
    unsigned int* rowlist = cnt + KCODES;

    _Float16* Xh = (_Float16*)out;
    _Float16* Xm = Xh + (size_t)N_ROWS * DIM;

    prep_k<<<10272, 256, 0, stream>>>(x, embed, Xh, Xm, Eh, Em, best, cnt, cs, partial, norm2);
    dist_k<<<(N_ROWS / BM) * (KCODES / BN), 256, 0, stream>>>(Xh, Xm, Eh, Em, norm2, best);
    quant_slot_k<<<N_ROWS / 4, 256, 0, stream>>>(embed, best, cnt, rowlist, out);
    csum_k<<<KCODES, 64, 0, stream>>>(x, eavg, cs, cnt, rowlist, best, partial, out);
}

// Round 16
// 1118.937 us; speedup vs baseline: 2.4838x; 2.4838x over previous
//
#include <hip/hip_runtime.h>
#include <stdint.h>

// Problem constants
#define N_ROWS 32768
#define KCODES 8192
#define DIM    512
#define DECAYF 0.8f
#define EPSF   1e-5f
#define CAP    96

// d_out layout (float32, reference return order)
#define OUT_QUANT 0
#define OUT_IND   (N_ROWS * DIM)
#define OUT_CSN   (OUT_IND + N_ROWS)
#define OUT_AVG   (OUT_CSN + KCODES)
#define OUT_NORM  (OUT_AVG + KCODES * DIM)

// During dist_k the quant region (64 MiB) holds Xh+Xm planes; rewritten by quant_slot_k.
// csn/avg/norm regions are written ONLY by csum_k (post-dist).
// ws: [0,256K) best; [256K,288K) norm2; [288K,+128) partial[32];
//     [1MiB) Eh, Em (8 MiB each);
//     [20MiB) cnt u32[8192]; ovcnt u32; rowlist u32[8192*CAP]; ovlist u32[32768].

typedef _Float16 f16x8 __attribute__((ext_vector_type(8)));
typedef __attribute__((ext_vector_type(4))) float f32x4;

__device__ __forceinline__ unsigned int enc_f(float v) {
    unsigned int b = __float_as_uint(v);
    return (b & 0x80000000u) ? ~b : (b | 0x80000000u);
}

__device__ __forceinline__ void gl16(const _Float16* g, const char* lds) {
    __builtin_amdgcn_global_load_lds(
        (const __attribute__((address_space(1))) unsigned int*)g,
        (__attribute__((address_space(3))) unsigned int*)lds, 16, 0, 0);
}

// ---- merged prep: [0,8192) split X (+best/cnt/ovcnt init); [8192,10240) split E (+norm2);
// ---- [10240,10272) partial cs sums (for S = 0.8*sum(cs) + 0.2*N_ROWS) ----
__global__ void prep_k(const float* __restrict__ x, const float* __restrict__ embed,
                       _Float16* __restrict__ Xh, _Float16* __restrict__ Xm,
                       _Float16* __restrict__ Eh, _Float16* __restrict__ Em,
                       unsigned long long* __restrict__ best, unsigned int* __restrict__ cnt,
                       unsigned int* __restrict__ ovcnt,
                       const float* __restrict__ cs, float* __restrict__ partial,
                       float* __restrict__ norm2) {
    if (blockIdx.x < 8192) {
        int i = blockIdx.x * 256 + threadIdx.x;        // < 2097152
        if (i < N_ROWS) best[i] = 0ull;
        if (i < KCODES) cnt[i] = 0u;
        if (i == 0) ovcnt[0] = 0u;
        const float4* s4 = (const float4*)x;
        float4 v0 = s4[(size_t)i * 2], v1 = s4[(size_t)i * 2 + 1];
        float f[8] = {v0.x, v0.y, v0.z, v0.w, v1.x, v1.y, v1.z, v1.w};
        f16x8 hv, mv;
        #pragma unroll
        for (int j = 0; j < 8; ++j) {
            _Float16 h = (_Float16)f[j];
            float r = f[j] - (float)h;
            hv[j] = h;
            mv[j] = (_Float16)(r * 1024.0f);
        }
        *(f16x8*)(Xh + (size_t)i * 8) = hv;
        *(f16x8*)(Xm + (size_t)i * 8) = mv;
    } else if (blockIdx.x < 10240) {
        int i = (blockIdx.x - 8192) * 256 + threadIdx.x;   // < 524288
        const float4* s4 = (const float4*)embed;
        float4 v0 = s4[(size_t)i * 2], v1 = s4[(size_t)i * 2 + 1];
        float f[8] = {v0.x, v0.y, v0.z, v0.w, v1.x, v1.y, v1.z, v1.w};
        f16x8 hv, mv;
        float s = 0.f;
        #pragma unroll
        for (int j = 0; j < 8; ++j) {
            _Float16 h = (_Float16)f[j];
            float r = f[j] - (float)h;
            hv[j] = h;
            mv[j] = (_Float16)(r * 1024.0f);
            s += f[j] * f[j];
        }
        *(f16x8*)(Eh + (size_t)i * 8) = hv;
        *(f16x8*)(Em + (size_t)i * 8) = mv;
        #pragma unroll
        for (int off = 32; off; off >>= 1) s += __shfl_down(s, off);
        if ((threadIdx.x & 63) == 0) norm2[i >> 6] = s;
    } else {
        // partial[b] = 0.8 * sum(cs[b*256 .. b*256+255])
        __shared__ float red[4];
        int b = blockIdx.x - 10240;                    // 0..31
        float s = DECAYF * cs[b * 256 + threadIdx.x];
        #pragma unroll
        for (int off = 32; off; off >>= 1) s += __shfl_down(s, off);
        if ((threadIdx.x & 63) == 0) red[threadIdx.x >> 6] = s;
        __syncthreads();
        if (threadIdx.x == 0) partial[b] = red[0] + red[1] + red[2] + red[3];
    }
}

// ---- K1: f16 3-pass dual-acc MFMA GEMM, counted-vmcnt 2-buffer pipeline (R6/R12, 846us) ----
#define BM 128
#define BN 128
#define BK 32
#define TILEB 8192      // bytes per plane tile: 128 rows x 32 f16
#define LBUF  32768     // one LDS buffer: 4 planes (Ah Am Bh Bm)

__global__ __launch_bounds__(256, 2) void dist_k(
    const _Float16* __restrict__ Xh, const _Float16* __restrict__ Xm,
    const _Float16* __restrict__ Eh, const _Float16* __restrict__ Em,
    const float* __restrict__ norm2, unsigned long long* __restrict__ best)
{
    __shared__ _Float16 smem[2 * 4 * 4096];   // 64 KiB: 2 x (Ah Am Bh Bm)
    char* sb = (char*)smem;

    const int tid = threadIdx.x;
    const int w = tid >> 6, l = tid & 63;

    // XCD column-band mapping: XCD (b&7) owns 8 consecutive bx; bx-minor, by-major.
    int b = blockIdx.x;
    int xcd = b & 7;
    int local = b >> 3;
    int bxl = local & 7;
    int by = local >> 3;
    int bx = xcd * 8 + bxl;
    const int rBase = by * BM, cBase = bx * BN;

    // staging: 2 rounds/plane, linear LDS dest, pre-swizzled source (granule ^ (row>>1)&3)
    int o0 = (w << 10) | (l << 4);
    int o1 = o0 + 4096;
    int row0 = o0 >> 6, kb0 = (o0 >> 4) & 3;
    int row1 = o1 >> 6, kb1 = (o1 >> 4) & 3;
    int c0 = (kb0 ^ ((row0 >> 1) & 3)) << 3;
    int c1 = (kb1 ^ ((row1 >> 1) & 3)) << 3;
    unsigned offA0 = (unsigned)(rBase + row0) * DIM + c0;
    unsigned offA1 = (unsigned)(rBase + row1) * DIM + c1;
    unsigned offB0 = (unsigned)(cBase + row0) * DIM + c0;
    unsigned offB1 = (unsigned)(cBase + row1) * DIM + c1;
    const int w1024 = w << 10;

    const int wr = w >> 1, wc = w & 1;     // 2x2 wave grid, 64x64 output each
    const int ln = l & 15, kq = l >> 4;

    // ds_read bases (proven conflict-free 16x16 geometry from R3)
    const int rA = wr * 64 + ln;
    const int baA = rA * 64 + ((kq ^ ((rA >> 1) & 3)) << 4);
    const int rB = wc * 64 + ln;
    const int baB = rB * 64 + ((kq ^ ((rB >> 1) & 3)) << 4);

    f32x4 acc1[4][4], acc2[4][4];
    #pragma unroll
    for (int i = 0; i < 4; ++i)
        #pragma unroll
        for (int j = 0; j < 4; ++j) {
            acc1[i][j] = (f32x4){0.f, 0.f, 0.f, 0.f};
            acc2[i][j] = (f32x4){0.f, 0.f, 0.f, 0.f};
        }

    #define STAGE(BUFOFF, D0) { \
        gl16(Xh + offA0 + (D0), sb + (BUFOFF) + 0 * TILEB + w1024); \
        gl16(Xh + offA1 + (D0), sb + (BUFOFF) + 0 * TILEB + 4096 + w1024); \
        gl16(Xm + offA0 + (D0), sb + (BUFOFF) + 1 * TILEB + w1024); \
        gl16(Xm + offA1 + (D0), sb + (BUFOFF) + 1 * TILEB + 4096 + w1024); \
        gl16(Eh + offB0 + (D0), sb + (BUFOFF) + 2 * TILEB + w1024); \
        gl16(Eh + offB1 + (D0), sb + (BUFOFF) + 2 * TILEB + 4096 + w1024); \
        gl16(Em + offB0 + (D0), sb + (BUFOFF) + 3 * TILEB + w1024); \
        gl16(Em + offB1 + (D0), sb + (BUFOFF) + 3 * TILEB + 4096 + w1024); \
    }

    #define COMPUTE(BUFOFF) { \
        f16x8 ah[4], am[4], bh[4], bm[4]; \
        _Pragma("unroll") \
        for (int ai = 0; ai < 4; ++ai) { \
            ah[ai] = *(const f16x8*)(sb + (BUFOFF) + 0 * TILEB + baA + ai * 1024); \
            am[ai] = *(const f16x8*)(sb + (BUFOFF) + 1 * TILEB + baA + ai * 1024); \
        } \
        _Pragma("unroll") \
        for (int bj = 0; bj < 4; ++bj) { \
            bh[bj] = *(const f16x8*)(sb + (BUFOFF) + 2 * TILEB + baB + bj * 1024); \
            bm[bj] = *(const f16x8*)(sb + (BUFOFF) + 3 * TILEB + baB + bj * 1024); \
        } \
        _Pragma("unroll") \
        for (int bj = 0; bj < 4; ++bj) \
            _Pragma("unroll") \
            for (int ai = 0; ai < 4; ++ai) \
                acc1[ai][bj] = __builtin_amdgcn_mfma_f32_16x16x32_f16(ah[ai], bh[bj], acc1[ai][bj], 0, 0, 0); \
        _Pragma("unroll") \
        for (int bj = 0; bj < 4; ++bj) \
            _Pragma("unroll") \
            for (int ai = 0; ai < 4; ++ai) \
                acc2[ai][bj] = __builtin_amdgcn_mfma_f32_16x16x32_f16(ah[ai], bm[bj], acc2[ai][bj], 0, 0, 0); \
        _Pragma("unroll") \
        for (int bj = 0; bj < 4; ++bj) \
            _Pragma("unroll") \
            for (int ai = 0; ai < 4; ++ai) \
                acc2[ai][bj] = __builtin_amdgcn_mfma_f32_16x16x32_f16(am[ai], bh[bj], acc2[ai][bj], 0, 0, 0); \
    }

    // T4 counted-vmcnt pipeline: never drain in-flight prefetch (R6-proven).
    STAGE(0, 0)
    #pragma unroll
    for (int it = 0; it < 8; ++it) {
        int d0 = it * 64;
        STAGE(LBUF, d0 + 32)
        asm volatile("s_waitcnt vmcnt(8)" ::: "memory");
        __builtin_amdgcn_s_barrier();
        __builtin_amdgcn_sched_barrier(0);
        COMPUTE(0)
        __builtin_amdgcn_s_barrier();
        if (it < 7) {
            STAGE(0, d0 + 64)
            asm volatile("s_waitcnt vmcnt(8)" ::: "memory");
        } else {
            asm volatile("s_waitcnt vmcnt(0)" ::: "memory");
        }
        __builtin_amdgcn_s_barrier();
        __builtin_amdgcn_sched_barrier(0);
        COMPUTE(LBUF)
        __builtin_amdgcn_s_barrier();
    }
    #undef STAGE
    #undef COMPUTE

    // ---- epilogue: dot = acc1 + 2^-10 * acc2 ; dist = 2*dot - ||e||^2 ; argmax ----
    const float S = 0.0009765625f;   // 2^-10
    float n2v[4];
    #pragma unroll
    for (int bj = 0; bj < 4; ++bj)
        n2v[bj] = norm2[cBase + wc * 64 + bj * 16 + ln];

    #pragma unroll
    for (int ai = 0; ai < 4; ++ai) {
        #pragma unroll
        for (int r = 0; r < 4; ++r) {
            float bval = -3.4e38f;
            int bidx = 0;
            #pragma unroll
            for (int bj = 0; bj < 4; ++bj) {
                float v = 2.f * (acc1[ai][bj][r] + S * acc2[ai][bj][r]) - n2v[bj];
                if (v > bval) { bval = v; bidx = cBase + wc * 64 + bj * 16 + ln; }
            }
            #pragma unroll
            for (int off = 1; off < 16; off <<= 1) {
                float ov = __shfl_xor(bval, off);
                int   oi = __shfl_xor(bidx, off);
                if (ov > bval || (ov == bval && oi < bidx)) { bval = ov; bidx = oi; }
            }
            if (ln == 0) {
                unsigned long long key =
                    ((unsigned long long)enc_f(bval) << 32) | (unsigned int)(~(unsigned int)bidx);
                atomicMax(&best[rBase + wr * 64 + ai * 16 + kq * 4 + r], key);
            }
        }
    }
}

// ---- phase A: gather quantize + slot allocation; overflow -> packed side-list ----
__global__ void quant_slot_k(const float* __restrict__ embed,
                             const unsigned long long* __restrict__ best,
                             unsigned int* __restrict__ cnt, unsigned int* __restrict__ ovcnt,
                             unsigned int* __restrict__ rowlist, unsigned int* __restrict__ ovlist,
                             float* __restrict__ out) {
    int row = blockIdx.x * 4 + (threadIdx.x >> 6);
    int lane = threadIdx.x & 63;
    int idx = (int)(~(unsigned int)best[row]);
    const float4* e = (const float4*)(embed + (size_t)idx * DIM);
    float4* q = (float4*)(out + OUT_QUANT + (size_t)row * DIM);
    q[lane] = e[lane];
    q[lane + 64] = e[lane + 64];
    if (lane == 0) {
        out[OUT_IND + row] = (float)idx;
        unsigned pos = atomicAdd(&cnt[idx], 1u);
        if (pos < CAP) {
            rowlist[idx * CAP + pos] = (unsigned)row;
        } else {
            unsigned opos = atomicAdd(ovcnt, 1u);
            ovlist[opos] = ((unsigned)idx << 16) | (unsigned)row;   // 13b code | 15b row
        }
    }
}

// ---- phase B: per-code fused EMA + smoothing + normalize (one block per code) ----
// csn = 0.8*cs + 0.2*n ; avg = 0.8*eavg + 0.2*sum ; S = 0.8*sum(cs) + 0.2*N_ROWS ;
// norm = avg * (S + K*eps) / ((csn+eps)*S).  Overflow rows come from the packed
// side-list (O(overflow) scan, not O(N_ROWS)).
__global__ void csum_k(const float* __restrict__ x, const float* __restrict__ eavg,
                       const float* __restrict__ cs, const unsigned int* __restrict__ cnt,
                       const unsigned int* __restrict__ ovcnt,
                       const unsigned int* __restrict__ rowlist,
                       const unsigned int* __restrict__ ovlist,
                       const float* __restrict__ partial, float* __restrict__ out) {
    int code = blockIdx.x, lane = threadIdx.x;
    int n = (int)cnt[code];
    int m = n < CAP ? n : CAP;
    float4 a0 = {0.f, 0.f, 0.f, 0.f}, a1 = {0.f, 0.f, 0.f, 0.f};
    for (int t = 0; t < m; ++t) {
        int row = (int)rowlist[code * CAP + t];
        const float4* xr = (const float4*)(x + (size_t)row * DIM);
        float4 v0 = xr[lane], v1 = xr[lane + 64];
        a0.x += v0.x; a0.y += v0.y; a0.z += v0.z; a0.w += v0.w;
        a1.x += v1.x; a1.y += v1.y; a1.z += v1.z; a1.w += v1.w;
    }
    if (n > CAP) {   // scan the small packed overflow list for this code's extra rows
        int ovn = (int)ovcnt[0];
        unsigned key = (unsigned)code << 16;
        for (int t = 0; t < ovn; ++t) {
            unsigned ent = ovlist[t];
            if ((ent & 0xFFFF0000u) != key) continue;
            int row = (int)(ent & 0xFFFFu);
            const float4* xr = (const float4*)(x + (size_t)row * DIM);
            float4 v0 = xr[lane], v1 = xr[lane + 64];
            a0.x += v0.x; a0.y += v0.y; a0.z += v0.z; a0.w += v0.w;
            a1.x += v1.x; a1.y += v1.y; a1.z += v1.z; a1.w += v1.w;
        }
    }
    float S = 0.2f * (float)N_ROWS;
    #pragma unroll
    for (int j = 0; j < 32; ++j) S += partial[j];
    float csn = DECAYF * cs[code] + 0.2f * (float)n;
    float inv = (S + (float)KCODES * EPSF) / ((csn + EPSF) * S);
    if (lane == 0) out[OUT_CSN + code] = csn;

    const float4* ev = (const float4*)(eavg + (size_t)code * DIM);
    float4 e0 = ev[lane], e1 = ev[lane + 64];
    float4 av0, av1, nm0, nm1;
    av0.x = DECAYF * e0.x + 0.2f * a0.x; av0.y = DECAYF * e0.y + 0.2f * a0.y;
    av0.z = DECAYF * e0.z + 0.2f * a0.z; av0.w = DECAYF * e0.w + 0.2f * a0.w;
    av1.x = DECAYF * e1.x + 0.2f * a1.x; av1.y = DECAYF * e1.y + 0.2f * a1.y;
    av1.z = DECAYF * e1.z + 0.2f * a1.z; av1.w = DECAYF * e1.w + 0.2f * a1.w;
    nm0.x = av0.x * inv; nm0.y = av0.y * inv; nm0.z = av0.z * inv; nm0.w = av0.w * inv;
    nm1.x = av1.x * inv; nm1.y = av1.y * inv; nm1.z = av1.z * inv; nm1.w = av1.w * inv;
    float4* av = (float4*)(out + OUT_AVG + (size_t)code * DIM);
    float4* nm = (float4*)(out + OUT_NORM + (size_t)code * DIM);
    av[lane] = av0; av[lane + 64] = av1;
    nm[lane] = nm0; nm[lane + 64] = nm1;
}

extern "C" void kernel_launch(void* const* d_in, const int* in_sizes, int n_in,
                              void* d_out, int out_size, void* d_ws, size_t ws_size,
                              hipStream_t stream) {
    const float* x     = (const float*)d_in[0];
    const float* embed = (const float*)d_in[1];
    const float* cs    = (const float*)d_in[2];
    const float* eavg  = (const float*)d_in[3];
    float* out = (float*)d_out;
    char*  w   = (char*)d_ws;

    unsigned long long* best = (unsigned long long*)w;
    float* norm2   = (float*)(w + 262144);
    float* partial = (float*)(w + 294912);
    _Float16* Eh = (_Float16*)(w + (1u << 20));
    _Float16* Em = Eh + (size_t)KCODES * DIM;
    unsigned int* cnt     = (unsigned int*)(w + (20u << 20));
    unsigned int* ovcnt   = cnt + KCODES;
    unsigned int* rowlist = cnt + KCODES + 64;            // 256B-aligned
    unsigned int* ovlist  = rowlist + (size_t)KCODES * CAP;

    _Float16* Xh = (_Float16*)out;
    _Float16* Xm = Xh + (size_t)N_ROWS * DIM;

    prep_k<<<10272, 256, 0, stream>>>(x, embed, Xh, Xm, Eh, Em, best, cnt, ovcnt, cs, partial, norm2);
    dist_k<<<(N_ROWS / BM) * (KCODES / BN), 256, 0, stream>>>(Xh, Xm, Eh, Em, norm2, best);
    quant_slot_k<<<N_ROWS / 4, 256, 0, stream>>>(embed, best, cnt, ovcnt, rowlist, ovlist, out);
    csum_k<<<KCODES, 64, 0, stream>>>(x, eavg, cs, cnt, ovcnt, rowlist, ovlist, partial, out);
}

// Round 17
// 911.136 us; speedup vs baseline: 3.0503x; 1.2281x over previous
//
#include <hip/hip_runtime.h>
#include <stdint.h>

// Problem constants
#define N_ROWS 32768
#define KCODES 8192
#define DIM    512
#define DECAYF 0.8f
#define EPSF   1e-5f
#define CAP    96

// d_out layout (float32, reference return order)
#define OUT_QUANT 0
#define OUT_IND   (N_ROWS * DIM)
#define OUT_CSN   (OUT_IND + N_ROWS)
#define OUT_AVG   (OUT_CSN + KCODES)
#define OUT_NORM  (OUT_AVG + KCODES * DIM)

// During dist_k the quant region (64 MiB) holds Xh+Xm planes (rewritten by quant_slot_k).
// The NORM region doubles as the overflow accumulator: zeroed by prep, atomically
// accumulated by quant_slot (raw x sums for codes past CAP), read then overwritten by csum.
// ws: [0,256K) best; [256K,288K) norm2; [288K,+128) partial[32];
//     [1MiB) Eh, Em (8 MiB each); [20MiB) cnt u32[8192]; [+pad] rowlist u32[8192*CAP].

typedef _Float16 f16x8 __attribute__((ext_vector_type(8)));
typedef __attribute__((ext_vector_type(4))) float f32x4;

__device__ __forceinline__ unsigned int enc_f(float v) {
    unsigned int b = __float_as_uint(v);
    return (b & 0x80000000u) ? ~b : (b | 0x80000000u);
}

__device__ __forceinline__ void gl16(const _Float16* g, const char* lds) {
    __builtin_amdgcn_global_load_lds(
        (const __attribute__((address_space(1))) unsigned int*)g,
        (__attribute__((address_space(3))) unsigned int*)lds, 16, 0, 0);
}

// ---- merged prep: [0,8192) split X (+best/cnt init + ovacc zero); [8192,10240) split E
// ---- (+norm2); [10240,10272) partial cs sums (S = 0.8*sum(cs) + 0.2*N_ROWS) ----
__global__ void prep_k(const float* __restrict__ x, const float* __restrict__ embed,
                       _Float16* __restrict__ Xh, _Float16* __restrict__ Xm,
                       _Float16* __restrict__ Eh, _Float16* __restrict__ Em,
                       unsigned long long* __restrict__ best, unsigned int* __restrict__ cnt,
                       const float* __restrict__ cs, float* __restrict__ partial,
                       float* __restrict__ norm2, float* __restrict__ out) {
    if (blockIdx.x < 8192) {
        int i = blockIdx.x * 256 + threadIdx.x;        // < 2097152
        if (i < N_ROWS) best[i] = 0ull;
        if (i < KCODES) cnt[i] = 0u;
        if (i < KCODES * DIM / 4)                      // zero overflow accumulator (norm region)
            ((float4*)(out + OUT_NORM))[i] = (float4){0.f, 0.f, 0.f, 0.f};
        const float4* s4 = (const float4*)x;
        float4 v0 = s4[(size_t)i * 2], v1 = s4[(size_t)i * 2 + 1];
        float f[8] = {v0.x, v0.y, v0.z, v0.w, v1.x, v1.y, v1.z, v1.w};
        f16x8 hv, mv;
        #pragma unroll
        for (int j = 0; j < 8; ++j) {
            _Float16 h = (_Float16)f[j];
            float r = f[j] - (float)h;
            hv[j] = h;
            mv[j] = (_Float16)(r * 1024.0f);
        }
        *(f16x8*)(Xh + (size_t)i * 8) = hv;
        *(f16x8*)(Xm + (size_t)i * 8) = mv;
    } else if (blockIdx.x < 10240) {
        int i = (blockIdx.x - 8192) * 256 + threadIdx.x;   // < 524288
        const float4* s4 = (const float4*)embed;
        float4 v0 = s4[(size_t)i * 2], v1 = s4[(size_t)i * 2 + 1];
        float f[8] = {v0.x, v0.y, v0.z, v0.w, v1.x, v1.y, v1.z, v1.w};
        f16x8 hv, mv;
        float s = 0.f;
        #pragma unroll
        for (int j = 0; j < 8; ++j) {
            _Float16 h = (_Float16)f[j];
            float r = f[j] - (float)h;
            hv[j] = h;
            mv[j] = (_Float16)(r * 1024.0f);
            s += f[j] * f[j];
        }
        *(f16x8*)(Eh + (size_t)i * 8) = hv;
        *(f16x8*)(Em + (size_t)i * 8) = mv;
        #pragma unroll
        for (int off = 32; off; off >>= 1) s += __shfl_down(s, off);
        if ((threadIdx.x & 63) == 0) norm2[i >> 6] = s;
    } else {
        __shared__ float red[4];
        int b = blockIdx.x - 10240;                    // 0..31
        float s = DECAYF * cs[b * 256 + threadIdx.x];
        #pragma unroll
        for (int off = 32; off; off >>= 1) s += __shfl_down(s, off);
        if ((threadIdx.x & 63) == 0) red[threadIdx.x >> 6] = s;
        __syncthreads();
        if (threadIdx.x == 0) partial[b] = red[0] + red[1] + red[2] + red[3];
    }
}

// ---- K1: f16 3-pass dual-acc MFMA GEMM, counted-vmcnt 2-buffer pipeline (R6/R12, 846us) ----
#define BM 128
#define BN 128
#define BK 32
#define TILEB 8192      // bytes per plane tile: 128 rows x 32 f16
#define LBUF  32768     // one LDS buffer: 4 planes (Ah Am Bh Bm)

__global__ __launch_bounds__(256, 2) void dist_k(
    const _Float16* __restrict__ Xh, const _Float16* __restrict__ Xm,
    const _Float16* __restrict__ Eh, const _Float16* __restrict__ Em,
    const float* __restrict__ norm2, unsigned long long* __restrict__ best)
{
    __shared__ _Float16 smem[2 * 4 * 4096];   // 64 KiB: 2 x (Ah Am Bh Bm)
    char* sb = (char*)smem;

    const int tid = threadIdx.x;
    const int w = tid >> 6, l = tid & 63;

    // XCD column-band mapping: XCD (b&7) owns 8 consecutive bx; bx-minor, by-major.
    int b = blockIdx.x;
    int xcd = b & 7;
    int local = b >> 3;
    int bxl = local & 7;
    int by = local >> 3;
    int bx = xcd * 8 + bxl;
    const int rBase = by * BM, cBase = bx * BN;

    // staging: 2 rounds/plane, linear LDS dest, pre-swizzled source (granule ^ (row>>1)&3)
    int o0 = (w << 10) | (l << 4);
    int o1 = o0 + 4096;
    int row0 = o0 >> 6, kb0 = (o0 >> 4) & 3;
    int row1 = o1 >> 6, kb1 = (o1 >> 4) & 3;
    int c0 = (kb0 ^ ((row0 >> 1) & 3)) << 3;
    int c1 = (kb1 ^ ((row1 >> 1) & 3)) << 3;
    unsigned offA0 = (unsigned)(rBase + row0) * DIM + c0;
    unsigned offA1 = (unsigned)(rBase + row1) * DIM + c1;
    unsigned offB0 = (unsigned)(cBase + row0) * DIM + c0;
    unsigned offB1 = (unsigned)(cBase + row1) * DIM + c1;
    const int w1024 = w << 10;

    const int wr = w >> 1, wc = w & 1;     // 2x2 wave grid, 64x64 output each
    const int ln = l & 15, kq = l >> 4;

    // ds_read bases (proven conflict-free 16x16 geometry from R3)
    const int rA = wr * 64 + ln;
    const int baA = rA * 64 + ((kq ^ ((rA >> 1) & 3)) << 4);
    const int rB = wc * 64 + ln;
    const int baB = rB * 64 + ((kq ^ ((rB >> 1) & 3)) << 4);

    f32x4 acc1[4][4], acc2[4][4];
    #pragma unroll
    for (int i = 0; i < 4; ++i)
        #pragma unroll
        for (int j = 0; j < 4; ++j) {
            acc1[i][j] = (f32x4){0.f, 0.f, 0.f, 0.f};
            acc2[i][j] = (f32x4){0.f, 0.f, 0.f, 0.f};
        }

    #define STAGE(BUFOFF, D0) { \
        gl16(Xh + offA0 + (D0), sb + (BUFOFF) + 0 * TILEB + w1024); \
        gl16(Xh + offA1 + (D0), sb + (BUFOFF) + 0 * TILEB + 4096 + w1024); \
        gl16(Xm + offA0 + (D0), sb + (BUFOFF) + 1 * TILEB + w1024); \
        gl16(Xm + offA1 + (D0), sb + (BUFOFF) + 1 * TILEB + 4096 + w1024); \
        gl16(Eh + offB0 + (D0), sb + (BUFOFF) + 2 * TILEB + w1024); \
        gl16(Eh + offB1 + (D0), sb + (BUFOFF) + 2 * TILEB + 4096 + w1024); \
        gl16(Em + offB0 + (D0), sb + (BUFOFF) + 3 * TILEB + w1024); \
        gl16(Em + offB1 + (D0), sb + (BUFOFF) + 3 * TILEB + 4096 + w1024); \
    }

    #define COMPUTE(BUFOFF) { \
        f16x8 ah[4], am[4], bh[4], bm[4]; \
        _Pragma("unroll") \
        for (int ai = 0; ai < 4; ++ai) { \
            ah[ai] = *(const f16x8*)(sb + (BUFOFF) + 0 * TILEB + baA + ai * 1024); \
            am[ai] = *(const f16x8*)(sb + (BUFOFF) + 1 * TILEB + baA + ai * 1024); \
        } \
        _Pragma("unroll") \
        for (int bj = 0; bj < 4; ++bj) { \
            bh[bj] = *(const f16x8*)(sb + (BUFOFF) + 2 * TILEB + baB + bj * 1024); \
            bm[bj] = *(const f16x8*)(sb + (BUFOFF) + 3 * TILEB + baB + bj * 1024); \
        } \
        _Pragma("unroll") \
        for (int bj = 0; bj < 4; ++bj) \
            _Pragma("unroll") \
            for (int ai = 0; ai < 4; ++ai) \
                acc1[ai][bj] = __builtin_amdgcn_mfma_f32_16x16x32_f16(ah[ai], bh[bj], acc1[ai][bj], 0, 0, 0); \
        _Pragma("unroll") \
        for (int bj = 0; bj < 4; ++bj) \
            _Pragma("unroll") \
            for (int ai = 0; ai < 4; ++ai) \
                acc2[ai][bj] = __builtin_amdgcn_mfma_f32_16x16x32_f16(ah[ai], bm[bj], acc2[ai][bj], 0, 0, 0); \
        _Pragma("unroll") \
        for (int bj = 0; bj < 4; ++bj) \
            _Pragma("unroll") \
            for (int ai = 0; ai < 4; ++ai) \
                acc2[ai][bj] = __builtin_amdgcn_mfma_f32_16x16x32_f16(am[ai], bh[bj], acc2[ai][bj], 0, 0, 0); \
    }

    // T4 counted-vmcnt pipeline: never drain in-flight prefetch (R6-proven).
    STAGE(0, 0)
    #pragma unroll
    for (int it = 0; it < 8; ++it) {
        int d0 = it * 64;
        STAGE(LBUF, d0 + 32)
        asm volatile("s_waitcnt vmcnt(8)" ::: "memory");
        __builtin_amdgcn_s_barrier();
        __builtin_amdgcn_sched_barrier(0);
        COMPUTE(0)
        __builtin_amdgcn_s_barrier();
        if (it < 7) {
            STAGE(0, d0 + 64)
            asm volatile("s_waitcnt vmcnt(8)" ::: "memory");
        } else {
            asm volatile("s_waitcnt vmcnt(0)" ::: "memory");
        }
        __builtin_amdgcn_s_barrier();
        __builtin_amdgcn_sched_barrier(0);
        COMPUTE(LBUF)
        __builtin_amdgcn_s_barrier();
    }
    #undef STAGE
    #undef COMPUTE

    // ---- epilogue: dot = acc1 + 2^-10 * acc2 ; dist = 2*dot - ||e||^2 ; argmax ----
    const float S = 0.0009765625f;   // 2^-10
    float n2v[4];
    #pragma unroll
    for (int bj = 0; bj < 4; ++bj)
        n2v[bj] = norm2[cBase + wc * 64 + bj * 16 + ln];

    #pragma unroll
    for (int ai = 0; ai < 4; ++ai) {
        #pragma unroll
        for (int r = 0; r < 4; ++r) {
            float bval = -3.4e38f;
            int bidx = 0;
            #pragma unroll
            for (int bj = 0; bj < 4; ++bj) {
                float v = 2.f * (acc1[ai][bj][r] + S * acc2[ai][bj][r]) - n2v[bj];
                if (v > bval) { bval = v; bidx = cBase + wc * 64 + bj * 16 + ln; }
            }
            #pragma unroll
            for (int off = 1; off < 16; off <<= 1) {
                float ov = __shfl_xor(bval, off);
                int   oi = __shfl_xor(bidx, off);
                if (ov > bval || (ov == bval && oi < bidx)) { bval = ov; bidx = oi; }
            }
            if (ln == 0) {
                unsigned long long key =
                    ((unsigned long long)enc_f(bval) << 32) | (unsigned int)(~(unsigned int)bidx);
                atomicMax(&best[rBase + wr * 64 + ai * 16 + kq * 4 + r], key);
            }
        }
    }
}

// ---- phase A: gather quantize + slot allocation; overflow rows scatter raw x
// ---- into the ovacc (norm region) via parallel per-row atomics (R14 mechanism) ----
__global__ void quant_slot_k(const float* __restrict__ x, const float* __restrict__ embed,
                             const unsigned long long* __restrict__ best,
                             unsigned int* __restrict__ cnt, unsigned int* __restrict__ rowlist,
                             float* __restrict__ out) {
    int row = blockIdx.x * 4 + (threadIdx.x >> 6);
    int lane = threadIdx.x & 63;
    int idx = (int)(~(unsigned int)best[row]);
    const float4* e = (const float4*)(embed + (size_t)idx * DIM);
    float4* q = (float4*)(out + OUT_QUANT + (size_t)row * DIM);
    q[lane] = e[lane];
    q[lane + 64] = e[lane + 64];
    int pos = 0;
    if (lane == 0) {
        out[OUT_IND + row] = (float)idx;
        pos = (int)atomicAdd(&cnt[idx], 1u);
        if (pos < CAP) rowlist[idx * CAP + pos] = (unsigned)row;
    }
    pos = __shfl(pos, 0);
    if (pos >= CAP) {   // parallel overflow scatter: raw x into ovacc (norm region)
        const float4* xr = (const float4*)(x + (size_t)row * DIM);
        float* ov = out + OUT_NORM + (size_t)idx * DIM;
        #pragma unroll
        for (int j = lane; j < DIM / 4; j += 64) {
            float4 xv = xr[j];
            atomicAdd(&ov[j * 4 + 0], xv.x);
            atomicAdd(&ov[j * 4 + 1], xv.y);
            atomicAdd(&ov[j * 4 + 2], xv.z);
            atomicAdd(&ov[j * 4 + 3], xv.w);
        }
    }
}

// ---- phase B: per-code fused EMA + smoothing + normalize (one block per code) ----
// csn = 0.8*cs + 0.2*n ; avg = 0.8*eavg + 0.2*(rowlist sum + ovacc) ;
// S = 0.8*sum(cs) + 0.2*N_ROWS ; norm = avg * (S + K*eps)/((csn+eps)*S).
// Reads ovacc from the norm region, then overwrites it with the final norm.
__global__ void csum_k(const float* __restrict__ x, const float* __restrict__ eavg,
                       const float* __restrict__ cs, const unsigned int* __restrict__ cnt,
                       const unsigned int* __restrict__ rowlist,
                       const float* __restrict__ partial, float* __restrict__ out) {
    int code = blockIdx.x, lane = threadIdx.x;
    int n = (int)cnt[code];
    int m = n < CAP ? n : CAP;
    float4 a0 = {0.f, 0.f, 0.f, 0.f}, a1 = {0.f, 0.f, 0.f, 0.f};
    for (int t = 0; t < m; ++t) {
        int row = (int)rowlist[code * CAP + t];
        const float4* xr = (const float4*)(x + (size_t)row * DIM);
        float4 v0 = xr[lane], v1 = xr[lane + 64];
        a0.x += v0.x; a0.y += v0.y; a0.z += v0.z; a0.w += v0.w;
        a1.x += v1.x; a1.y += v1.y; a1.z += v1.z; a1.w += v1.w;
    }
    if (n > CAP) {   // add the parallel-accumulated overflow sums (one row read)
        const float4* ov = (const float4*)(out + OUT_NORM + (size_t)code * DIM);
        float4 o0 = ov[lane], o1 = ov[lane + 64];
        a0.x += o0.x; a0.y += o0.y; a0.z += o0.z; a0.w += o0.w;
        a1.x += o1.x; a1.y += o1.y; a1.z += o1.z; a1.w += o1.w;
    }
    float S = 0.2f * (float)N_ROWS;
    #pragma unroll
    for (int j = 0; j < 32; ++j) S += partial[j];
    float csn = DECAYF * cs[code] + 0.2f * (float)n;
    float inv = (S + (float)KCODES * EPSF) / ((csn + EPSF) * S);
    if (lane == 0) out[OUT_CSN + code] = csn;

    const float4* ev = (const float4*)(eavg + (size_t)code * DIM);
    float4 e0 = ev[lane], e1 = ev[lane + 64];
    float4 av0, av1, nm0, nm1;
    av0.x = DECAYF * e0.x + 0.2f * a0.x; av0.y = DECAYF * e0.y + 0.2f * a0.y;
    av0.z = DECAYF * e0.z + 0.2f * a0.z; av0.w = DECAYF * e0.w + 0.2f * a0.w;
    av1.x = DECAYF * e1.x + 0.2f * a1.x; av1.y = DECAYF * e1.y + 0.2f * a1.y;
    av1.z = DECAYF * e1.z + 0.2f * a1.z; av1.w = DECAYF * e1.w + 0.2f * a1.w;
    nm0.x = av0.x * inv; nm0.y = av0.y * inv; nm0.z = av0.z * inv; nm0.w = av0.w * inv;
    nm1.x = av1.x * inv; nm1.y = av1.y * inv; nm1.z = av1.z * inv; nm1.w = av1.w * inv;
    float4* av = (float4*)(out + OUT_AVG + (size_t)code * DIM);
    float4* nm = (float4*)(out + OUT_NORM + (size_t)code * DIM);
    av[lane] = av0; av[lane + 64] = av1;
    nm[lane] = nm0; nm[lane + 64] = nm1;
}

extern "C" void kernel_launch(void* const* d_in, const int* in_sizes, int n_in,
                              void* d_out, int out_size, void* d_ws, size_t ws_size,
                              hipStream_t stream) {
    const float* x     = (const float*)d_in[0];
    const float* embed = (const float*)d_in[1];
    const float* cs    = (const float*)d_in[2];
    const float* eavg  = (const float*)d_in[3];
    float* out = (float*)d_out;
    char*  w   = (char*)d_ws;

    unsigned long long* best = (unsigned long long*)w;
    float* norm2   = (float*)(w + 262144);
    float* partial = (float*)(w + 294912);
    _Float16* Eh = (_Float16*)(w + (1u << 20));
    _Float16* Em = Eh + (size_t)KCODES * DIM;
    unsigned int* cnt     = (unsigned int*)(w + (20u << 20));
    unsigned int* rowlist = cnt + KCODES + 64;            // 256B-aligned

    _Float16* Xh = (_Float16*)out;
    _Float16* Xm = Xh + (size_t)N_ROWS * DIM;

    prep_k<<<10272, 256, 0, stream>>>(x, embed, Xh, Xm, Eh, Em, best, cnt, cs, partial, norm2, out);
    dist_k<<<(N_ROWS / BM) * (KCODES / BN), 256, 0, stream>>>(Xh, Xm, Eh, Em, norm2, best);
    quant_slot_k<<<N_ROWS / 4, 256, 0, stream>>>(x, embed, best, cnt, rowlist, out);
    csum_k<<<KCODES, 64, 0, stream>>>(x, eavg, cs, cnt, rowlist, partial, out);
}

// Round 18
// 908.015 us; speedup vs baseline: 3.0608x; 1.0034x over previous
//
#include <hip/hip_runtime.h>
#include <stdint.h>

// Problem constants
#define N_ROWS 32768
#define KCODES 8192
#define DIM    512
#define DECAYF 0.8f
#define EPSF   1e-5f
#define CAP    96

// d_out layout (float32, reference return order)
#define OUT_QUANT 0
#define OUT_IND   (N_ROWS * DIM)
#define OUT_CSN   (OUT_IND + N_ROWS)
#define OUT_AVG   (OUT_CSN + KCODES)
#define OUT_NORM  (OUT_AVG + KCODES * DIM)

// During dist_k the quant region (64 MiB) holds Xh+Xm planes (rewritten by quant_slot_k).
// The NORM region doubles as the overflow accumulator: zeroed by prep, atomically
// accumulated by quant_slot (raw x sums for codes past CAP), read then overwritten by csum.
// ws: [0,256K) best; [256K,288K) norm2; [288K,+128) partial[32];
//     [1MiB) Eh, Em (8 MiB each); [20MiB) cnt u32[8192]; [+pad] rowlist u32[8192*CAP].

typedef _Float16 f16x8 __attribute__((ext_vector_type(8)));
typedef __attribute__((ext_vector_type(4))) float f32x4;

__device__ __forceinline__ unsigned int enc_f(float v) {
    unsigned int b = __float_as_uint(v);
    return (b & 0x80000000u) ? ~b : (b | 0x80000000u);
}

__device__ __forceinline__ void gl16(const _Float16* g, const char* lds) {
    __builtin_amdgcn_global_load_lds(
        (const __attribute__((address_space(1))) unsigned int*)g,
        (__attribute__((address_space(3))) unsigned int*)lds, 16, 0, 0);
}

// ---- merged prep: [0,8192) split X (+best/cnt init + ovacc zero); [8192,10240) split E
// ---- (+norm2); [10240,10272) partial cs sums (S = 0.8*sum(cs) + 0.2*N_ROWS) ----
__global__ void prep_k(const float* __restrict__ x, const float* __restrict__ embed,
                       _Float16* __restrict__ Xh, _Float16* __restrict__ Xm,
                       _Float16* __restrict__ Eh, _Float16* __restrict__ Em,
                       unsigned long long* __restrict__ best, unsigned int* __restrict__ cnt,
                       const float* __restrict__ cs, float* __restrict__ partial,
                       float* __restrict__ norm2, float* __restrict__ out) {
    if (blockIdx.x < 8192) {
        int i = blockIdx.x * 256 + threadIdx.x;        // < 2097152
        if (i < N_ROWS) best[i] = 0ull;
        if (i < KCODES) cnt[i] = 0u;
        if (i < KCODES * DIM / 4)                      // zero overflow accumulator (norm region)
            ((float4*)(out + OUT_NORM))[i] = (float4){0.f, 0.f, 0.f, 0.f};
        const float4* s4 = (const float4*)x;
        float4 v0 = s4[(size_t)i * 2], v1 = s4[(size_t)i * 2 + 1];
        float f[8] = {v0.x, v0.y, v0.z, v0.w, v1.x, v1.y, v1.z, v1.w};
        f16x8 hv, mv;
        #pragma unroll
        for (int j = 0; j < 8; ++j) {
            _Float16 h = (_Float16)f[j];
            float r = f[j] - (float)h;
            hv[j] = h;
            mv[j] = (_Float16)(r * 1024.0f);
        }
        *(f16x8*)(Xh + (size_t)i * 8) = hv;
        *(f16x8*)(Xm + (size_t)i * 8) = mv;
    } else if (blockIdx.x < 10240) {
        int i = (blockIdx.x - 8192) * 256 + threadIdx.x;   // < 524288
        const float4* s4 = (const float4*)embed;
        float4 v0 = s4[(size_t)i * 2], v1 = s4[(size_t)i * 2 + 1];
        float f[8] = {v0.x, v0.y, v0.z, v0.w, v1.x, v1.y, v1.z, v1.w};
        f16x8 hv, mv;
        float s = 0.f;
        #pragma unroll
        for (int j = 0; j < 8; ++j) {
            _Float16 h = (_Float16)f[j];
            float r = f[j] - (float)h;
            hv[j] = h;
            mv[j] = (_Float16)(r * 1024.0f);
            s += f[j] * f[j];
        }
        *(f16x8*)(Eh + (size_t)i * 8) = hv;
        *(f16x8*)(Em + (size_t)i * 8) = mv;
        #pragma unroll
        for (int off = 32; off; off >>= 1) s += __shfl_down(s, off);
        if ((threadIdx.x & 63) == 0) norm2[i >> 6] = s;
    } else {
        __shared__ float red[4];
        int b = blockIdx.x - 10240;                    // 0..31
        float s = DECAYF * cs[b * 256 + threadIdx.x];
        #pragma unroll
        for (int off = 32; off; off >>= 1) s += __shfl_down(s, off);
        if ((threadIdx.x & 63) == 0) red[threadIdx.x >> 6] = s;
        __syncthreads();
        if (threadIdx.x == 0) partial[b] = red[0] + red[1] + red[2] + red[3];
    }
}

// ---- K1: f16 3-pass dual-acc MFMA GEMM, counted-vmcnt 2-buffer pipeline (R6/R12, 846us) ----
#define BM 128
#define BN 128
#define BK 32
#define TILEB 8192      // bytes per plane tile: 128 rows x 32 f16
#define LBUF  32768     // one LDS buffer: 4 planes (Ah Am Bh Bm)

__global__ __launch_bounds__(256, 2) void dist_k(
    const _Float16* __restrict__ Xh, const _Float16* __restrict__ Xm,
    const _Float16* __restrict__ Eh, const _Float16* __restrict__ Em,
    const float* __restrict__ norm2, unsigned long long* __restrict__ best)
{
    __shared__ _Float16 smem[2 * 4 * 4096];   // 64 KiB: 2 x (Ah Am Bh Bm)
    char* sb = (char*)smem;

    const int tid = threadIdx.x;
    const int w = tid >> 6, l = tid & 63;

    // XCD column-band mapping: XCD (b&7) owns 8 consecutive bx; bx-minor, by-major.
    int b = blockIdx.x;
    int xcd = b & 7;
    int local = b >> 3;
    int bxl = local & 7;
    int by = local >> 3;
    int bx = xcd * 8 + bxl;
    const int rBase = by * BM, cBase = bx * BN;

    // staging: 2 rounds/plane, linear LDS dest, pre-swizzled source (granule ^ (row>>1)&3)
    int o0 = (w << 10) | (l << 4);
    int o1 = o0 + 4096;
    int row0 = o0 >> 6, kb0 = (o0 >> 4) & 3;
    int row1 = o1 >> 6, kb1 = (o1 >> 4) & 3;
    int c0 = (kb0 ^ ((row0 >> 1) & 3)) << 3;
    int c1 = (kb1 ^ ((row1 >> 1) & 3)) << 3;
    unsigned offA0 = (unsigned)(rBase + row0) * DIM + c0;
    unsigned offA1 = (unsigned)(rBase + row1) * DIM + c1;
    unsigned offB0 = (unsigned)(cBase + row0) * DIM + c0;
    unsigned offB1 = (unsigned)(cBase + row1) * DIM + c1;
    const int w1024 = w << 10;

    const int wr = w >> 1, wc = w & 1;     // 2x2 wave grid, 64x64 output each
    const int ln = l & 15, kq = l >> 4;

    // ds_read bases (proven conflict-free 16x16 geometry from R3)
    const int rA = wr * 64 + ln;
    const int baA = rA * 64 + ((kq ^ ((rA >> 1) & 3)) << 4);
    const int rB = wc * 64 + ln;
    const int baB = rB * 64 + ((kq ^ ((rB >> 1) & 3)) << 4);

    f32x4 acc1[4][4], acc2[4][4];
    #pragma unroll
    for (int i = 0; i < 4; ++i)
        #pragma unroll
        for (int j = 0; j < 4; ++j) {
            acc1[i][j] = (f32x4){0.f, 0.f, 0.f, 0.f};
            acc2[i][j] = (f32x4){0.f, 0.f, 0.f, 0.f};
        }

    #define STAGE(BUFOFF, D0) { \
        gl16(Xh + offA0 + (D0), sb + (BUFOFF) + 0 * TILEB + w1024); \
        gl16(Xh + offA1 + (D0), sb + (BUFOFF) + 0 * TILEB + 4096 + w1024); \
        gl16(Xm + offA0 + (D0), sb + (BUFOFF) + 1 * TILEB + w1024); \
        gl16(Xm + offA1 + (D0), sb + (BUFOFF) + 1 * TILEB + 4096 + w1024); \
        gl16(Eh + offB0 + (D0), sb + (BUFOFF) + 2 * TILEB + w1024); \
        gl16(Eh + offB1 + (D0), sb + (BUFOFF) + 2 * TILEB + 4096 + w1024); \
        gl16(Em + offB0 + (D0), sb + (BUFOFF) + 3 * TILEB + w1024); \
        gl16(Em + offB1 + (D0), sb + (BUFOFF) + 3 * TILEB + 4096 + w1024); \
    }

    #define COMPUTE(BUFOFF) { \
        f16x8 ah[4], am[4], bh[4], bm[4]; \
        _Pragma("unroll") \
        for (int ai = 0; ai < 4; ++ai) { \
            ah[ai] = *(const f16x8*)(sb + (BUFOFF) + 0 * TILEB + baA + ai * 1024); \
            am[ai] = *(const f16x8*)(sb + (BUFOFF) + 1 * TILEB + baA + ai * 1024); \
        } \
        _Pragma("unroll") \
        for (int bj = 0; bj < 4; ++bj) { \
            bh[bj] = *(const f16x8*)(sb + (BUFOFF) + 2 * TILEB + baB + bj * 1024); \
            bm[bj] = *(const f16x8*)(sb + (BUFOFF) + 3 * TILEB + baB + bj * 1024); \
        } \
        _Pragma("unroll") \
        for (int bj = 0; bj < 4; ++bj) \
            _Pragma("unroll") \
            for (int ai = 0; ai < 4; ++ai) \
                acc1[ai][bj] = __builtin_amdgcn_mfma_f32_16x16x32_f16(ah[ai], bh[bj], acc1[ai][bj], 0, 0, 0); \
        _Pragma("unroll") \
        for (int bj = 0; bj < 4; ++bj) \
            _Pragma("unroll") \
            for (int ai = 0; ai < 4; ++ai) \
                acc2[ai][bj] = __builtin_amdgcn_mfma_f32_16x16x32_f16(ah[ai], bm[bj], acc2[ai][bj], 0, 0, 0); \
        _Pragma("unroll") \
        for (int bj = 0; bj < 4; ++bj) \
            _Pragma("unroll") \
            for (int ai = 0; ai < 4; ++ai) \
                acc2[ai][bj] = __builtin_amdgcn_mfma_f32_16x16x32_f16(am[ai], bh[bj], acc2[ai][bj], 0, 0, 0); \
    }

    // T4 counted-vmcnt pipeline: never drain in-flight prefetch (R6-proven).
    STAGE(0, 0)
    #pragma unroll
    for (int it = 0; it < 8; ++it) {
        int d0 = it * 64;
        STAGE(LBUF, d0 + 32)
        asm volatile("s_waitcnt vmcnt(8)" ::: "memory");
        __builtin_amdgcn_s_barrier();
        __builtin_amdgcn_sched_barrier(0);
        COMPUTE(0)
        __builtin_amdgcn_s_barrier();
        if (it < 7) {
            STAGE(0, d0 + 64)
            asm volatile("s_waitcnt vmcnt(8)" ::: "memory");
        } else {
            asm volatile("s_waitcnt vmcnt(0)" ::: "memory");
        }
        __builtin_amdgcn_s_barrier();
        __builtin_amdgcn_sched_barrier(0);
        COMPUTE(LBUF)
        __builtin_amdgcn_s_barrier();
    }
    #undef STAGE
    #undef COMPUTE

    // ---- epilogue: dot = acc1 + 2^-10 * acc2 ; dist = 2*dot - ||e||^2 ; argmax ----
    const float S = 0.0009765625f;   // 2^-10
    float n2v[4];
    #pragma unroll
    for (int bj = 0; bj < 4; ++bj)
        n2v[bj] = norm2[cBase + wc * 64 + bj * 16 + ln];

    #pragma unroll
    for (int ai = 0; ai < 4; ++ai) {
        #pragma unroll
        for (int r = 0; r < 4; ++r) {
            float bval = -3.4e38f;
            int bidx = 0;
            #pragma unroll
            for (int bj = 0; bj < 4; ++bj) {
                float v = 2.f * (acc1[ai][bj][r] + S * acc2[ai][bj][r]) - n2v[bj];
                if (v > bval) { bval = v; bidx = cBase + wc * 64 + bj * 16 + ln; }
            }
            #pragma unroll
            for (int off = 1; off < 16; off <<= 1) {
                float ov = __shfl_xor(bval, off);
                int   oi = __shfl_xor(bidx, off);
                if (ov > bval || (ov == bval && oi < bidx)) { bval = ov; bidx = oi; }
            }
            if (ln == 0) {
                unsigned long long key =
                    ((unsigned long long)enc_f(bval) << 32) | (unsigned int)(~(unsigned int)bidx);
                atomicMax(&best[rBase + wr * 64 + ai * 16 + kq * 4 + r], key);
            }
        }
    }
}

// ---- phase A: gather quantize + slot allocation; overflow rows scatter raw x
// ---- into the ovacc (norm region) via parallel per-row atomics (R14 mechanism) ----
__global__ void quant_slot_k(const float* __restrict__ x, const float* __restrict__ embed,
                             const unsigned long long* __restrict__ best,
                             unsigned int* __restrict__ cnt, unsigned int* __restrict__ rowlist,
                             float* __restrict__ out) {
    int row = blockIdx.x * 4 + (threadIdx.x >> 6);
    int lane = threadIdx.x & 63;
    int idx = (int)(~(unsigned int)best[row]);
    const float4* e = (const float4*)(embed + (size_t)idx * DIM);
    float4* q = (float4*)(out + OUT_QUANT + (size_t)row * DIM);
    q[lane] = e[lane];
    q[lane + 64] = e[lane + 64];
    int pos = 0;
    if (lane == 0) {
        out[OUT_IND + row] = (float)idx;
        pos = (int)atomicAdd(&cnt[idx], 1u);
        if (pos < CAP) rowlist[idx * CAP + pos] = (unsigned)row;
    }
    pos = __shfl(pos, 0);
    if (pos >= CAP) {   // parallel overflow scatter: raw x into ovacc (norm region)
        const float4* xr = (const float4*)(x + (size_t)row * DIM);
        float* ov = out + OUT_NORM + (size_t)idx * DIM;
        #pragma unroll
        for (int j = lane; j < DIM / 4; j += 64) {
            float4 xv = xr[j];
            atomicAdd(&ov[j * 4 + 0], xv.x);
            atomicAdd(&ov[j * 4 + 1], xv.y);
            atomicAdd(&ov[j * 4 + 2], xv.z);
            atomicAdd(&ov[j * 4 + 3], xv.w);
        }
    }
}

// ---- phase B: per-code fused EMA + smoothing + normalize (128 threads per code) ----
// csn = 0.8*cs + 0.2*n ; avg = 0.8*eavg + 0.2*(rowlist sum + ovacc) ;
// S = 0.8*sum(cs) + 0.2*N_ROWS ; norm = avg * (S + K*eps)/((csn+eps)*S).
// 128 lanes x one float4 each covers DIM=512 exactly; doubles straggler-block BW
// for heavily-loaded codes vs the 64-thread version.
__global__ void csum_k(const float* __restrict__ x, const float* __restrict__ eavg,
                       const float* __restrict__ cs, const unsigned int* __restrict__ cnt,
                       const unsigned int* __restrict__ rowlist,
                       const float* __restrict__ partial, float* __restrict__ out) {
    int code = blockIdx.x, lane = threadIdx.x;   // 128 threads
    int n = (int)cnt[code];
    int m = n < CAP ? n : CAP;
    float4 a0 = {0.f, 0.f, 0.f, 0.f};
    for (int t = 0; t < m; ++t) {
        int row = (int)rowlist[code * CAP + t];
        float4 v0 = ((const float4*)(x + (size_t)row * DIM))[lane];
        a0.x += v0.x; a0.y += v0.y; a0.z += v0.z; a0.w += v0.w;
    }
    if (n > CAP) {   // add the parallel-accumulated overflow sums (one row read)
        float4 o0 = ((const float4*)(out + OUT_NORM + (size_t)code * DIM))[lane];
        a0.x += o0.x; a0.y += o0.y; a0.z += o0.z; a0.w += o0.w;
    }
    float S = 0.2f * (float)N_ROWS;
    #pragma unroll
    for (int j = 0; j < 32; ++j) S += partial[j];
    float csn = DECAYF * cs[code] + 0.2f * (float)n;
    float inv = (S + (float)KCODES * EPSF) / ((csn + EPSF) * S);
    if (lane == 0) out[OUT_CSN + code] = csn;

    float4 e0 = ((const float4*)(eavg + (size_t)code * DIM))[lane];
    float4 av0, nm0;
    av0.x = DECAYF * e0.x + 0.2f * a0.x; av0.y = DECAYF * e0.y + 0.2f * a0.y;
    av0.z = DECAYF * e0.z + 0.2f * a0.z; av0.w = DECAYF * e0.w + 0.2f * a0.w;
    nm0.x = av0.x * inv; nm0.y = av0.y * inv; nm0.z = av0.z * inv; nm0.w = av0.w * inv;
    ((float4*)(out + OUT_AVG  + (size_t)code * DIM))[lane] = av0;
    ((float4*)(out + OUT_NORM + (size_t)code * DIM))[lane] = nm0;
}

extern "C" void kernel_launch(void* const* d_in, const int* in_sizes, int n_in,
                              void* d_out, int out_size, void* d_ws, size_t ws_size,
                              hipStream_t stream) {
    const float* x     = (const float*)d_in[0];
    const float* embed = (const float*)d_in[1];
    const float* cs    = (const float*)d_in[2];
    const float* eavg  = (const float*)d_in[3];
    float* out = (float*)d_out;
    char*  w   = (char*)d_ws;

    unsigned long long* best = (unsigned long long*)w;
    float* norm2   = (float*)(w + 262144);
    float* partial = (float*)(w + 294912);
    _Float16* Eh = (_Float16*)(w + (1u << 20));
    _Float16* Em = Eh + (size_t)KCODES * DIM;
    unsigned int* cnt     = (unsigned int*)(w + (20u << 20));
    unsigned int* rowlist = cnt + KCODES + 64;            // 256B-aligned

    _Float16* Xh = (_Float16*)out;
    _Float16* Xm = Xh + (size_t)N_ROWS * DIM;

    prep_k<<<10272, 256, 0, stream>>>(x, embed, Xh, Xm, Eh, Em, best, cnt, cs, partial, norm2, out);
    dist_k<<<(N_ROWS / BM) * (KCODES / BN), 256, 0, stream>>>(Xh, Xm, Eh, Em, norm2, best);
    quant_slot_k<<<N_ROWS / 4, 256, 0, stream>>>(x, embed, best, cnt, rowlist, out);
    csum_k<<<KCODES, 128, 0, stream>>>(x, eavg, cs, cnt, rowlist, partial, out);
}